// Round 1
// baseline (176.960 us; speedup 1.0000x reference)
//
#include <hip/hip_runtime.h>
#include <math.h>

typedef _Float16 f16;
typedef _Float16 half4_t __attribute__((ext_vector_type(4)));
typedef _Float16 half8_t __attribute__((ext_vector_type(8)));
typedef float floatx4 __attribute__((ext_vector_type(4)));

#define LDATA_OFF_BYTES 86016  // after W1t(16384B) + W2t(32768B) + W3t(36864B)

// ------------------------------------------------------------------
// Kernel P: repack weights fp32 -> f16, transposed [col][k] so B-operand
// fragments (k-chunks of 8) are contiguous 16B loads.
// ------------------------------------------------------------------
__global__ __launch_bounds__(256) void prep_weights(
    const float* __restrict__ W1, const float* __restrict__ W2,
    const float* __restrict__ W3, f16* __restrict__ wt) {
  int t = blockIdx.x * 256 + threadIdx.x;
  if (t < 8192) {                       // W1t [128][64]
    int c = t >> 6, k = t & 63;
    wt[t] = (f16)W1[k * 128 + c];
  } else if (t < 24576) {               // W2t [128][128]
    int u = t - 8192;
    int c = u >> 7, k = u & 127;
    wt[t] = (f16)W2[k * 128 + c];
  } else if (t < 43008) {               // W3t [144][128], cols 136..143 zero
    int u = t - 24576;
    int c = u >> 7, k = u & 127;
    wt[t] = (f16)((c < 136) ? W3[k * 136 + c] : 0.0f);
  }
}

// ------------------------------------------------------------------
// fast tanh: tanh(x) = 1 - 2/(e^{2x}+1), via v_exp_f32 + v_rcp_f32 (~1e-6 abs)
// ------------------------------------------------------------------
__device__ __forceinline__ float fast_tanh(float v) {
  float e = __builtin_amdgcn_exp2f(v * 2.885390081777926814f);  // 2*log2(e)
  return 1.0f - 2.0f * __builtin_amdgcn_rcpf(e + 1.0f);
}

// ------------------------------------------------------------------
// Kernel M: fused 3-layer MLP. block = 256 thr = 4 waves; 64 batch rows/block,
// 16 rows/wave. MFMA 16x16x32 f16, fp32 accum. C->A transpose via per-wave LDS.
// ------------------------------------------------------------------
__global__ __launch_bounds__(256) void mlp_kernel(
    const float* __restrict__ x, const float* __restrict__ b1,
    const float* __restrict__ b2, const float* __restrict__ b3,
    const f16* __restrict__ wt, f16* __restrict__ ldata) {
  __shared__ f16 hb[2][4][16][136];  // 128 cols + 8 pad (bank-conflict-free)
  const int tid = threadIdx.x;
  const int wave = tid >> 6;
  const int lane = tid & 63;
  const int cl = lane & 15;  // A-row / C-col index
  const int q = lane >> 4;   // quad: k-chunk / C-row-group
  const int r0 = blockIdx.x * 64 + wave * 16;

  const f16* w1t = wt;           // [128][64]
  const f16* w2t = wt + 8192;    // [128][128]
  const f16* w3t = wt + 24576;   // [144][128]

  // ---- Layer 1: [16x64] @ [64x128] ----
  half8_t a0, a1;
  {
    const float* xr = x + (size_t)(r0 + cl) * 64 + q * 8;
    floatx4 v0 = *(const floatx4*)(xr);
    floatx4 v1 = *(const floatx4*)(xr + 4);
    floatx4 v2 = *(const floatx4*)(xr + 32);
    floatx4 v3 = *(const floatx4*)(xr + 36);
#pragma unroll
    for (int i = 0; i < 4; ++i) {
      a0[i] = (f16)v0[i]; a0[i + 4] = (f16)v1[i];
      a1[i] = (f16)v2[i]; a1[i + 4] = (f16)v3[i];
    }
  }
#pragma unroll
  for (int c8 = 0; c8 < 8; ++c8) {
    int c = c8 * 16 + cl;
    half8_t w0 = *(const half8_t*)(w1t + c * 64 + q * 8);
    half8_t w1v = *(const half8_t*)(w1t + c * 64 + 32 + q * 8);
    floatx4 acc = {0.f, 0.f, 0.f, 0.f};
    acc = __builtin_amdgcn_mfma_f32_16x16x32_f16(a0, w0, acc, 0, 0, 0);
    acc = __builtin_amdgcn_mfma_f32_16x16x32_f16(a1, w1v, acc, 0, 0, 0);
    float bias = b1[c];
#pragma unroll
    for (int i = 0; i < 4; ++i) {
      float v = acc[i] + bias;
      v = v > 0.f ? v : 0.01f * v;  // LeakyReLU
      hb[0][wave][q * 4 + i][c] = (f16)v;
    }
  }
  __syncthreads();

  // ---- Layer 2: [16x128] @ [128x128] ----
  half8_t ha[4];
#pragma unroll
  for (int ks = 0; ks < 4; ++ks)
    ha[ks] = *(const half8_t*)(&hb[0][wave][cl][ks * 32 + q * 8]);
#pragma unroll
  for (int c8 = 0; c8 < 8; ++c8) {
    int c = c8 * 16 + cl;
    floatx4 acc = {0.f, 0.f, 0.f, 0.f};
#pragma unroll
    for (int ks = 0; ks < 4; ++ks) {
      half8_t wv = *(const half8_t*)(w2t + c * 128 + ks * 32 + q * 8);
      acc = __builtin_amdgcn_mfma_f32_16x16x32_f16(ha[ks], wv, acc, 0, 0, 0);
    }
    float bias = b2[c];
#pragma unroll
    for (int i = 0; i < 4; ++i) {
      float v = acc[i] + bias;
      v = v > 0.f ? v : 0.01f * v;
      hb[1][wave][q * 4 + i][c] = (f16)v;
    }
  }
  __syncthreads();

  // ---- Layer 3: [16x128] @ [128x136] + tanh ----
#pragma unroll
  for (int ks = 0; ks < 4; ++ks)
    ha[ks] = *(const half8_t*)(&hb[1][wave][cl][ks * 32 + q * 8]);
#pragma unroll
  for (int c8 = 0; c8 < 9; ++c8) {
    int c = c8 * 16 + cl;  // 0..143
    floatx4 acc = {0.f, 0.f, 0.f, 0.f};
#pragma unroll
    for (int ks = 0; ks < 4; ++ks) {
      half8_t wv = *(const half8_t*)(w3t + c * 128 + ks * 32 + q * 8);
      acc = __builtin_amdgcn_mfma_f32_16x16x32_f16(ha[ks], wv, acc, 0, 0, 0);
    }
    if (c < 136) {
      float bias = b3[c];
#pragma unroll
      for (int i = 0; i < 4; ++i) {
        float v = acc[i] + bias;
        ldata[(size_t)(r0 + q * 4 + i) * 136 + c] = (f16)fast_tanh(v);
      }
    }
  }
}

// ------------------------------------------------------------------
// Expm kernel helpers. One wave per 16x16 symmetric matrix; every fragment
// lives in the canonical symmetric layout: lane value_i = X[l&15][4*(l>>4)+i]
// which (by symmetry) is simultaneously a valid A-operand, B-operand and C/D
// layout for v_mfma_f32_16x16x16_f16 -> no cross-lane movement ever.
// ------------------------------------------------------------------
__device__ __forceinline__ float wred_sum(float v) {
#pragma unroll
  for (int m = 1; m < 64; m <<= 1) v += __shfl_xor(v, m);
  return v;
}
__device__ __forceinline__ float wred_max(float v) {
#pragma unroll
  for (int m = 1; m < 64; m <<= 1) v = fmaxf(v, __shfl_xor(v, m));
  return v;
}
// Gershgorin upper bound: max_r ( X[r][r] + sum_{k!=r} |X[r][k]| )
__device__ __forceinline__ float gersh(const float* b, const float* dg) {
  float part = 0.f;
#pragma unroll
  for (int i = 0; i < 4; ++i) part += (dg[i] != 0.f) ? b[i] : fabsf(b[i]);
  part += __shfl_xor(part, 16);
  part += __shfl_xor(part, 32);
#pragma unroll
  for (int m = 1; m < 16; m <<= 1) part = fmaxf(part, __shfl_xor(part, m));
  return part;
}
// split fp32 -> f16 hi + f16 lo (rel err ~2^-22 when recombined via 3 MFMAs)
__device__ __forceinline__ void split4(const float* v, half4_t& h, half4_t& l) {
#pragma unroll
  for (int i = 0; i < 4; ++i) {
    f16 a = (f16)v[i];
    h[i] = a;
    l[i] = (f16)(v[i] - (float)a);
  }
}
// z = x*y with split precision: xh*yh + xh*yl + xl*yh, fp32 MFMA accumulate
__device__ __forceinline__ void mm3(half4_t xh, half4_t xl, half4_t yh,
                                    half4_t yl, float* z) {
  floatx4 acc = {0.f, 0.f, 0.f, 0.f};
  acc = __builtin_amdgcn_mfma_f32_16x16x16f16(xh, yl, acc, 0, 0, 0);
  acc = __builtin_amdgcn_mfma_f32_16x16x16f16(xl, yh, acc, 0, 0, 0);
  acc = __builtin_amdgcn_mfma_f32_16x16x16f16(xh, yh, acc, 0, 0, 0);
#pragma unroll
  for (int i = 0; i < 4; ++i) z[i] = acc[i];
}
// degree-9 Taylor of expm via Paterson-Stockmeyer (4 matmuls), ||b||_2 <= 1
__device__ __forceinline__ void taylor9(const float* b, const float* dg,
                                        float* p) {
  half4_t bh, bl;
  split4(b, bh, bl);
  float a2[4];
  mm3(bh, bl, bh, bl, a2);
  half4_t a2h, a2l;
  split4(a2, a2h, a2l);
  float a3[4];
  mm3(bh, bl, a2h, a2l, a3);
  half4_t a3h, a3l;
  split4(a3, a3h, a3l);
  const float C3 = 1.f / 6.f, C4 = 1.f / 24.f, C5 = 1.f / 120.f;
  const float C6 = 1.f / 720.f, C7 = 1.f / 5040.f, C8 = 1.f / 40320.f,
              C9 = 1.f / 362880.f;
  float t[4];
#pragma unroll
  for (int i = 0; i < 4; ++i)
    t[i] = C6 * dg[i] + C7 * b[i] + C8 * a2[i] + C9 * a3[i];
  half4_t th, tl;
  split4(t, th, tl);
  mm3(a3h, a3l, th, tl, p);
#pragma unroll
  for (int i = 0; i < 4; ++i) p[i] += C3 * dg[i] + C4 * b[i] + C5 * a2[i];
  split4(p, th, tl);
  mm3(a3h, a3l, th, tl, p);
#pragma unroll
  for (int i = 0; i < 4; ++i) p[i] += dg[i] + b[i] + 0.5f * a2[i];
}

// ------------------------------------------------------------------
// Kernel E: out = normalize_F( expm( expm(2Q)/2 ) )   [the eigh-free identity]
// ------------------------------------------------------------------
__global__ __launch_bounds__(256) void expm_kernel(
    const f16* __restrict__ ldata, float* __restrict__ out) {
  const int lane = threadIdx.x & 63;
  const int mat = (int)((blockIdx.x * 256u + threadIdx.x) >> 6);
  const int r = lane & 15, q = lane >> 4;
  const f16* ld = ldata + (size_t)mat * 136;

  float b[4], dg[4];
#pragma unroll
  for (int i = 0; i < 4; ++i) {
    int k = q * 4 + i;
    int hi = r > k ? r : k;
    int lo = r + k - hi;
    float v = (float)ld[hi * (hi + 1) / 2 + lo];  // tril row-major index
    dg[i] = (r == k) ? 1.f : 0.f;
    b[i] = (r == k) ? 4.f * v : 2.f * v;  // b = 2*Q (Q diag = 2*ldata)
  }

  // ---- expm #1: Z = expm(2Q), exact scale (shift + power-of-2 tracking) ----
  float c1 = gersh(b, dg);
#pragma unroll
  for (int i = 0; i < 4; ++i) b[i] -= c1 * dg[i];  // spectrum <= 0
  float fr = sqrtf(wred_sum(b[0] * b[0] + b[1] * b[1] + b[2] * b[2] + b[3] * b[3]));
  int e1;
  frexpf(fr, &e1);
  int s1 = e1 < 0 ? 0 : (e1 > 24 ? 24 : e1);
  float sc = ldexpf(1.f, -s1);
#pragma unroll
  for (int i = 0; i < 4; ++i) b[i] *= sc;
  float p[4];
  taylor9(b, dg, p);
  int F = 0;  // invariant: expm(2Q - c1 I) = p * 2^F at loop end
  for (int k2 = 0; k2 < s1; ++k2) {
    float m = wred_max(fmaxf(fmaxf(fabsf(p[0]), fabsf(p[1])),
                             fmaxf(fabsf(p[2]), fabsf(p[3]))));
    int e;
    frexpf(m, &e);
    float rs = ldexpf(1.f, -e);
#pragma unroll
    for (int i = 0; i < 4; ++i) p[i] *= rs;
    F = 2 * (F + e);
    half4_t ph, pl;
    split4(p, ph, pl);
    mm3(ph, pl, ph, pl, p);
  }
  // Z/2 = 0.5 * e^{c1} * 2^F * p
  float fac = exp2f(c1 * 1.4426950408889634f + (float)F - 1.0f);
#pragma unroll
  for (int i = 0; i < 4; ++i) b[i] = fac * p[i];

  // ---- expm #2: M = expm(Z/2), scale-free (normalization kills scalars) ----
  float c2 = gersh(b, dg);
#pragma unroll
  for (int i = 0; i < 4; ++i) b[i] -= c2 * dg[i];
  fr = sqrtf(wred_sum(b[0] * b[0] + b[1] * b[1] + b[2] * b[2] + b[3] * b[3]));
  int e2;
  frexpf(fr, &e2);
  int s2 = e2 < 0 ? 0 : (e2 > 24 ? 24 : e2);
  sc = ldexpf(1.f, -s2);
#pragma unroll
  for (int i = 0; i < 4; ++i) b[i] *= sc;
  taylor9(b, dg, p);
  for (int k2 = 0; k2 < s2; ++k2) {
    float m = wred_max(fmaxf(fmaxf(fabsf(p[0]), fabsf(p[1])),
                             fmaxf(fabsf(p[2]), fabsf(p[3]))));
    float rs = 1.0f / fmaxf(m, 1e-30f);
#pragma unroll
    for (int i = 0; i < 4; ++i) p[i] *= rs;
    half4_t ph, pl;
    split4(p, ph, pl);
    mm3(ph, pl, ph, pl, p);
  }

  // ---- normalize by Frobenius norm, write (float4 per lane, contiguous) ----
  float n2 = wred_sum(p[0] * p[0] + p[1] * p[1] + p[2] * p[2] + p[3] * p[3]);
  float inv = 1.0f / sqrtf(n2);
  floatx4 o;
#pragma unroll
  for (int i = 0; i < 4; ++i) o[i] = p[i] * inv;
  // value_i = M[4q+i][r] = M[r][4q+i]  ->  out[mat*256 + r*16 + 4q + i]
  *(floatx4*)(out + (size_t)mat * 256 + r * 16 + q * 4) = o;
}

// ------------------------------------------------------------------
extern "C" void kernel_launch(void* const* d_in, const int* in_sizes, int n_in,
                              void* d_out, int out_size, void* d_ws,
                              size_t ws_size, hipStream_t stream) {
  const float* x = (const float*)d_in[0];
  const float* W1 = (const float*)d_in[1];
  const float* b1 = (const float*)d_in[2];
  const float* W2 = (const float*)d_in[3];
  const float* b2 = (const float*)d_in[4];
  const float* W3 = (const float*)d_in[5];
  const float* b3 = (const float*)d_in[6];
  float* out = (float*)d_out;
  f16* wt = (f16*)d_ws;
  f16* ldata = (f16*)((char*)d_ws + LDATA_OFF_BYTES);

  prep_weights<<<168, 256, 0, stream>>>(W1, W2, W3, wt);
  mlp_kernel<<<1024, 256, 0, stream>>>(x, b1, b2, b3, wt, ldata);
  expm_kernel<<<16384, 256, 0, stream>>>(ldata, out);
}

// Round 2
// 170.428 us; speedup vs baseline: 1.0383x; 1.0383x over previous
//
#include <hip/hip_runtime.h>
#include <math.h>

typedef _Float16 f16;
typedef _Float16 half4_t __attribute__((ext_vector_type(4)));
typedef _Float16 half8_t __attribute__((ext_vector_type(8)));
typedef float floatx4 __attribute__((ext_vector_type(4)));

#define LDATA_OFF_BYTES 86016  // after W1t(16384B) + W2t(32768B) + W3t(36864B)

// ------------------------------------------------------------------
// Kernel P: repack weights fp32 -> f16, transposed [col][k] so B-operand
// fragments (k-chunks of 8) are contiguous 16B loads.
// ------------------------------------------------------------------
__global__ __launch_bounds__(256) void prep_weights(
    const float* __restrict__ W1, const float* __restrict__ W2,
    const float* __restrict__ W3, f16* __restrict__ wt) {
  int t = blockIdx.x * 256 + threadIdx.x;
  if (t < 8192) {                       // W1t [128][64]
    int c = t >> 6, k = t & 63;
    wt[t] = (f16)W1[k * 128 + c];
  } else if (t < 24576) {               // W2t [128][128]
    int u = t - 8192;
    int c = u >> 7, k = u & 127;
    wt[t] = (f16)W2[k * 128 + c];
  } else if (t < 43008) {               // W3t [144][128], cols 136..143 zero
    int u = t - 24576;
    int c = u >> 7, k = u & 127;
    wt[t] = (f16)((c < 136) ? W3[k * 136 + c] : 0.0f);
  }
}

// ------------------------------------------------------------------
// fast tanh: tanh(x) = 1 - 2/(e^{2x}+1), via v_exp_f32 + v_rcp_f32 (~1e-6 abs)
// ------------------------------------------------------------------
__device__ __forceinline__ float fast_tanh(float v) {
  float e = __builtin_amdgcn_exp2f(v * 2.885390081777926814f);  // 2*log2(e)
  return 1.0f - 2.0f * __builtin_amdgcn_rcpf(e + 1.0f);
}

// ------------------------------------------------------------------
// Kernel M: fused 3-layer MLP. block = 256 thr = 4 waves; 64 batch rows/block,
// 16 rows/wave. MFMA 16x16x32 f16, fp32 accum. C->A transpose via per-wave LDS.
// ------------------------------------------------------------------
__global__ __launch_bounds__(256) void mlp_kernel(
    const float* __restrict__ x, const float* __restrict__ b1,
    const float* __restrict__ b2, const float* __restrict__ b3,
    const f16* __restrict__ wt, f16* __restrict__ ldata) {
  __shared__ f16 hb[2][4][16][136];  // 128 cols + 8 pad (bank-conflict-free)
  const int tid = threadIdx.x;
  const int wave = tid >> 6;
  const int lane = tid & 63;
  const int cl = lane & 15;  // A-row / C-col index
  const int q = lane >> 4;   // quad: k-chunk / C-row-group
  const int r0 = blockIdx.x * 64 + wave * 16;

  const f16* w1t = wt;           // [128][64]
  const f16* w2t = wt + 8192;    // [128][128]
  const f16* w3t = wt + 24576;   // [144][128]

  // ---- Layer 1: [16x64] @ [64x128] ----
  half8_t a0, a1;
  {
    const float* xr = x + (size_t)(r0 + cl) * 64 + q * 8;
    floatx4 v0 = *(const floatx4*)(xr);
    floatx4 v1 = *(const floatx4*)(xr + 4);
    floatx4 v2 = *(const floatx4*)(xr + 32);
    floatx4 v3 = *(const floatx4*)(xr + 36);
#pragma unroll
    for (int i = 0; i < 4; ++i) {
      a0[i] = (f16)v0[i]; a0[i + 4] = (f16)v1[i];
      a1[i] = (f16)v2[i]; a1[i + 4] = (f16)v3[i];
    }
  }
#pragma unroll
  for (int c8 = 0; c8 < 8; ++c8) {
    int c = c8 * 16 + cl;
    half8_t w0 = *(const half8_t*)(w1t + c * 64 + q * 8);
    half8_t w1v = *(const half8_t*)(w1t + c * 64 + 32 + q * 8);
    floatx4 acc = {0.f, 0.f, 0.f, 0.f};
    acc = __builtin_amdgcn_mfma_f32_16x16x32_f16(a0, w0, acc, 0, 0, 0);
    acc = __builtin_amdgcn_mfma_f32_16x16x32_f16(a1, w1v, acc, 0, 0, 0);
    float bias = b1[c];
#pragma unroll
    for (int i = 0; i < 4; ++i) {
      float v = acc[i] + bias;
      v = v > 0.f ? v : 0.01f * v;  // LeakyReLU
      hb[0][wave][q * 4 + i][c] = (f16)v;
    }
  }
  __syncthreads();

  // ---- Layer 2: [16x128] @ [128x128] ----
  half8_t ha[4];
#pragma unroll
  for (int ks = 0; ks < 4; ++ks)
    ha[ks] = *(const half8_t*)(&hb[0][wave][cl][ks * 32 + q * 8]);
#pragma unroll
  for (int c8 = 0; c8 < 8; ++c8) {
    int c = c8 * 16 + cl;
    floatx4 acc = {0.f, 0.f, 0.f, 0.f};
#pragma unroll
    for (int ks = 0; ks < 4; ++ks) {
      half8_t wv = *(const half8_t*)(w2t + c * 128 + ks * 32 + q * 8);
      acc = __builtin_amdgcn_mfma_f32_16x16x32_f16(ha[ks], wv, acc, 0, 0, 0);
    }
    float bias = b2[c];
#pragma unroll
    for (int i = 0; i < 4; ++i) {
      float v = acc[i] + bias;
      v = v > 0.f ? v : 0.01f * v;
      hb[1][wave][q * 4 + i][c] = (f16)v;
    }
  }
  __syncthreads();

  // ---- Layer 3: [16x128] @ [128x136] + tanh ----
#pragma unroll
  for (int ks = 0; ks < 4; ++ks)
    ha[ks] = *(const half8_t*)(&hb[1][wave][cl][ks * 32 + q * 8]);
#pragma unroll
  for (int c8 = 0; c8 < 9; ++c8) {
    int c = c8 * 16 + cl;  // 0..143
    floatx4 acc = {0.f, 0.f, 0.f, 0.f};
#pragma unroll
    for (int ks = 0; ks < 4; ++ks) {
      half8_t wv = *(const half8_t*)(w3t + c * 128 + ks * 32 + q * 8);
      acc = __builtin_amdgcn_mfma_f32_16x16x32_f16(ha[ks], wv, acc, 0, 0, 0);
    }
    if (c < 136) {
      float bias = b3[c];
#pragma unroll
      for (int i = 0; i < 4; ++i) {
        float v = acc[i] + bias;
        ldata[(size_t)(r0 + q * 4 + i) * 136 + c] = (f16)fast_tanh(v);
      }
    }
  }
}

// ------------------------------------------------------------------
// Expm kernel. One wave per 16x16 symmetric matrix; canonical symmetric
// fragment layout: lane value_i = X[l&15][4*(l>>4)+i], simultaneously a valid
// A, B and C/D layout for v_mfma_f32_16x16x16_f16 -> zero cross-lane moves.
// All elementwise math on floatx4 so the compiler emits v_pk_*_f32.
// ------------------------------------------------------------------

// split fp32 -> f16 hi + f16 lo via packed RTZ converts (recombined ~2^-21)
__device__ __forceinline__ void split(floatx4 v, half4_t& h, half4_t& l) {
  auto h01 = __builtin_amdgcn_cvt_pkrtz(v[0], v[1]);
  auto h23 = __builtin_amdgcn_cvt_pkrtz(v[2], v[3]);
  floatx4 hf = {(float)h01[0], (float)h01[1], (float)h23[0], (float)h23[1]};
  floatx4 d = v - hf;
  auto l01 = __builtin_amdgcn_cvt_pkrtz(d[0], d[1]);
  auto l23 = __builtin_amdgcn_cvt_pkrtz(d[2], d[3]);
  h[0] = h01[0]; h[1] = h01[1]; h[2] = h23[0]; h[3] = h23[1];
  l[0] = l01[0]; l[1] = l01[1]; l[2] = l23[0]; l[3] = l23[1];
}

// z = x*y + acc with split precision: xh*yl + xl*yh + xh*yh, fp32 MFMA accum
__device__ __forceinline__ floatx4 mm3(half4_t xh, half4_t xl, half4_t yh,
                                       half4_t yl, floatx4 acc) {
  acc = __builtin_amdgcn_mfma_f32_16x16x16f16(xh, yl, acc, 0, 0, 0);
  acc = __builtin_amdgcn_mfma_f32_16x16x16f16(xl, yh, acc, 0, 0, 0);
  acc = __builtin_amdgcn_mfma_f32_16x16x16f16(xh, yh, acc, 0, 0, 0);
  return acc;
}

// degree-9 Taylor via Paterson-Stockmeyer (4 products), spectral(b) <= 1.
// Constant-term matrices are preloaded into the MFMA accumulator.
__device__ __forceinline__ floatx4 taylor9(floatx4 b, floatx4 I4) {
  const float C3 = 1.f / 6.f, C4 = 1.f / 24.f, C5 = 1.f / 120.f;
  const float C6 = 1.f / 720.f, C7 = 1.f / 5040.f, C8 = 1.f / 40320.f,
              C9 = 1.f / 362880.f;
  half4_t bh, bl;
  split(b, bh, bl);
  floatx4 zero = {0.f, 0.f, 0.f, 0.f};
  floatx4 a2 = mm3(bh, bl, bh, bl, zero);
  half4_t a2h, a2l;
  split(a2, a2h, a2l);
  floatx4 a3 = mm3(bh, bl, a2h, a2l, zero);
  half4_t a3h, a3l;
  split(a3, a3h, a3l);
  floatx4 t = a3 * C9 + a2 * C8 + b * C7 + I4 * C6;
  half4_t th, tl;
  split(t, th, tl);
  floatx4 acc1 = a2 * C5 + b * C4 + I4 * C3;
  floatx4 p = mm3(a3h, a3l, th, tl, acc1);
  half4_t ph, pl;
  split(p, ph, pl);
  floatx4 acc2 = a2 * 0.5f + b + I4;
  return mm3(a3h, a3l, ph, pl, acc2);
}

// p = expm(B - m I), m = trace/16 (centered shift). One dual 6-step shuffle
// reduction yields both trace and ||B||_F^2; s chosen from exponent bits so
// spectral(scaled) <= 1; squarings need no rescale (entries <= e^{fr'}).
__device__ __forceinline__ floatx4 expm_centered(floatx4 b, floatx4 I4,
                                                 float& m) {
  float s2 = b[0] * b[0] + b[1] * b[1] + b[2] * b[2] + b[3] * b[3];
  float td = I4[0] * b[0] + I4[1] * b[1] + I4[2] * b[2] + I4[3] * b[3];
#pragma unroll
  for (int msk = 1; msk < 64; msk <<= 1) {
    s2 += __shfl_xor(s2, msk);
    td += __shfl_xor(td, msk);
  }
  m = td * 0.0625f;
  float frp2 = fmaxf(s2 - td * m, 1e-30f);  // ||B - mI||_F^2
  int e2 = (int)(__float_as_uint(frp2) >> 23) - 127;
  int s = (e2 + 2) >> 1;
  s = s < 0 ? 0 : (s > 30 ? 30 : s);
  s = __builtin_amdgcn_readfirstlane(s);
  float sc = __uint_as_float((unsigned)(127 - s) << 23);  // 2^-s
  b = (b - I4 * m) * sc;
  floatx4 p = taylor9(b, I4);
  for (int k = 0; k < s; ++k) {
    half4_t ph, pl;
    split(p, ph, pl);
    floatx4 zero = {0.f, 0.f, 0.f, 0.f};
    p = mm3(ph, pl, ph, pl, zero);
  }
  return p;
}

// out = normalize_F( expm( expm(2Q)/2 ) )   [the eigh-free identity]
__global__ __launch_bounds__(256) void expm_kernel(
    const f16* __restrict__ ldata, float* __restrict__ out) {
  const int lane = threadIdx.x & 63;
  const int mat = (int)((blockIdx.x * 256u + threadIdx.x) >> 6);
  const int r = lane & 15, q = lane >> 4;
  const f16* ld = ldata + (size_t)mat * 136;

  floatx4 b, I4;
#pragma unroll
  for (int i = 0; i < 4; ++i) {
    int k = q * 4 + i;
    int hi = r > k ? r : k;
    int lo = r + k - hi;
    float v = (float)ld[hi * (hi + 1) / 2 + lo];  // tril row-major index
    bool d = (r == k);
    I4[i] = d ? 1.f : 0.f;
    b[i] = d ? 4.f * v : 2.f * v;  // b = 2*Q (Q diag = 2*ldata)
  }

  // ---- expm #1: p = expm(2Q - m1 I);  Z/2 = e^{m1}/2 * p (exact algebra) ----
  float m1;
  floatx4 p = expm_centered(b, I4, m1);
  float fac = __builtin_amdgcn_exp2f(m1 * 1.4426950408889634f - 1.0f);
  b = p * fac;

  // ---- expm #2: shift constant cancels in the final normalization ----
  float m2;
  p = expm_centered(b, I4, m2);

  // ---- normalize by Frobenius norm, write (float4 per lane, contiguous) ----
  float n2 = p[0] * p[0] + p[1] * p[1] + p[2] * p[2] + p[3] * p[3];
#pragma unroll
  for (int msk = 1; msk < 64; msk <<= 1) n2 += __shfl_xor(n2, msk);
  float inv = __builtin_amdgcn_rsqf(n2);
  floatx4 o = p * inv;
  // value_i = M[4q+i][r] = M[r][4q+i]  ->  out[mat*256 + r*16 + 4q + i]
  *(floatx4*)(out + (size_t)mat * 256 + r * 16 + q * 4) = o;
}

// ------------------------------------------------------------------
extern "C" void kernel_launch(void* const* d_in, const int* in_sizes, int n_in,
                              void* d_out, int out_size, void* d_ws,
                              size_t ws_size, hipStream_t stream) {
  const float* x = (const float*)d_in[0];
  const float* W1 = (const float*)d_in[1];
  const float* b1 = (const float*)d_in[2];
  const float* W2 = (const float*)d_in[3];
  const float* b2 = (const float*)d_in[4];
  const float* W3 = (const float*)d_in[5];
  const float* b3 = (const float*)d_in[6];
  float* out = (float*)d_out;
  f16* wt = (f16*)d_ws;
  f16* ldata = (f16*)((char*)d_ws + LDATA_OFF_BYTES);

  prep_weights<<<168, 256, 0, stream>>>(W1, W2, W3, wt);
  mlp_kernel<<<1024, 256, 0, stream>>>(x, b1, b2, b3, wt, ldata);
  expm_kernel<<<16384, 256, 0, stream>>>(ldata, out);
}

// Round 3
// 145.300 us; speedup vs baseline: 1.2179x; 1.1729x over previous
//
#include <hip/hip_runtime.h>
#include <math.h>

typedef _Float16 f16;
typedef _Float16 half4_t __attribute__((ext_vector_type(4)));
typedef _Float16 half8_t __attribute__((ext_vector_type(8)));
typedef float floatx4 __attribute__((ext_vector_type(4)));

// ------------------------------------------------------------------
// Kernel P: repack weights fp32 -> f16, transposed [col][k] so B-operand
// fragments (k-chunks of 8) are contiguous 16B loads.
// ------------------------------------------------------------------
__global__ __launch_bounds__(256) void prep_weights(
    const float* __restrict__ W1, const float* __restrict__ W2,
    const float* __restrict__ W3, f16* __restrict__ wt) {
  int t = blockIdx.x * 256 + threadIdx.x;
  if (t < 8192) {                       // W1t [128][64]
    int c = t >> 6, k = t & 63;
    wt[t] = (f16)W1[k * 128 + c];
  } else if (t < 24576) {               // W2t [128][128]
    int u = t - 8192;
    int c = u >> 7, k = u & 127;
    wt[t] = (f16)W2[k * 128 + c];
  } else if (t < 43008) {               // W3t [144][128], cols 136..143 zero
    int u = t - 24576;
    int c = u >> 7, k = u & 127;
    wt[t] = (f16)((c < 136) ? W3[k * 136 + c] : 0.0f);
  }
}

// fast tanh: tanh(x) = 1 - 2/(e^{2x}+1)
__device__ __forceinline__ float fast_tanh(float v) {
  float e = __builtin_amdgcn_exp2f(v * 2.885390081777926814f);  // 2*log2(e)
  return 1.0f - 2.0f * __builtin_amdgcn_rcpf(e + 1.0f);
}

// ---- DPP wave64 sum: row_shr 1/2/4/8 then row_bcast 15/31; total in lane 63.
template <int CTRL>
__device__ __forceinline__ float dpp_add(float v) {
  int t = __builtin_amdgcn_update_dpp(0, __builtin_bit_cast(int, v), CTRL,
                                      0xf, 0xf, true);
  return v + __builtin_bit_cast(float, t);
}
__device__ __forceinline__ float wsum(float v) {
  v = dpp_add<0x111>(v);  // row_shr:1
  v = dpp_add<0x112>(v);  // row_shr:2
  v = dpp_add<0x114>(v);  // row_shr:4
  v = dpp_add<0x118>(v);  // row_shr:8
  v = dpp_add<0x142>(v);  // row_bcast:15
  v = dpp_add<0x143>(v);  // row_bcast:31
  return __builtin_bit_cast(
      float, __builtin_amdgcn_readlane(__builtin_bit_cast(int, v), 63));
}

// round floatx4 -> half4 via packed RTZ converts
__device__ __forceinline__ half4_t to_h(floatx4 v) {
  auto p0 = __builtin_amdgcn_cvt_pkrtz(v[0], v[1]);
  auto p1 = __builtin_amdgcn_cvt_pkrtz(v[2], v[3]);
  half4_t h;
  h[0] = p0[0]; h[1] = p0[1]; h[2] = p1[0]; h[3] = p1[1];
  return h;
}

// ------------------------------------------------------------------
// p = expm(B - m I), m = trace/16. Canonical symmetric fragment layout:
// lane value_i = X[l&15][4*(l>>4)+i] is simultaneously a valid A, B and C/D
// layout for v_mfma_f32_16x16x16_f16 (all products are commuting polynomials
// of one symmetric matrix -> results stay symmetric, zero cross-lane moves).
// Degree-4 Paterson-Stockmeyer with spectral bound theta <= 0.354 via
// Frobenius-based power-of-2 scaling; squarings need no rescale.
// ------------------------------------------------------------------
__device__ __forceinline__ floatx4 expm_c(floatx4 b, floatx4 I4, float& m) {
  float s2 = wsum(b[0] * b[0] + b[1] * b[1] + b[2] * b[2] + b[3] * b[3]);
  float td = wsum(I4[0] * b[0] + I4[1] * b[1] + I4[2] * b[2] + I4[3] * b[3]);
  m = td * 0.0625f;
  float fr2 = fmaxf(s2 - td * m, 1e-30f);  // ||B - mI||_F^2
  int e2 = (int)(__builtin_bit_cast(unsigned, fr2) >> 23) - 127;
  int s = (e2 + 5) >> 1;  // guarantees 2^-s * fr <= 2^-1.5 = 0.354
  s = s < 0 ? 0 : (s > 12 ? 12 : s);
  s = __builtin_amdgcn_readfirstlane(s);
  float sc = __builtin_bit_cast(float, (unsigned)(127 - s) << 23);  // 2^-s
  b = (b - I4 * m) * sc;
  half4_t bh = to_h(b);
  floatx4 zero = {0.f, 0.f, 0.f, 0.f};
  floatx4 a2 = __builtin_amdgcn_mfma_f32_16x16x16f16(bh, bh, zero, 0, 0, 0);
  // deg-4 Taylor: I + b + a2*(I/2 + b/6 + a2/24)
  floatx4 t = I4 * 0.5f + b * (1.f / 6.f) + a2 * (1.f / 24.f);
  floatx4 p = __builtin_amdgcn_mfma_f32_16x16x16f16(to_h(a2), to_h(t), I4 + b,
                                                    0, 0, 0);
  for (int k = 0; k < s; ++k) {
    half4_t ph = to_h(p);
    p = __builtin_amdgcn_mfma_f32_16x16x16f16(ph, ph, zero, 0, 0, 0);
  }
  return p;
}

// ------------------------------------------------------------------
// Fused kernel: 1 wave per block, 16 batch rows per block.
// Phase A: 3-layer MLP via 16x16x32 MFMA (LDS transpose between layers).
// Phase B: for each of the 16 rows, out = normalize_F(expm(expm(2Q)/2)).
// Single-wave blocks: in-order per-wave DS pipe replaces __syncthreads.
// ------------------------------------------------------------------
__global__ __launch_bounds__(64) void fused_kernel(
    const float* __restrict__ x, const float* __restrict__ b1,
    const float* __restrict__ b2v, const float* __restrict__ b3,
    const f16* __restrict__ wt, float* __restrict__ out) {
  __shared__ f16 hb[16][136];  // row stride 272B = 17*16B (b128-aligned)
  const int lane = threadIdx.x & 63;
  const int cl = lane & 15;  // A-row / C-col index
  const int q = lane >> 4;   // quad: k-chunk / C-row-group
  const int r0 = blockIdx.x * 16;

  const f16* w1t = wt;           // [128][64]
  const f16* w2t = wt + 8192;    // [128][128]
  const f16* w3t = wt + 24576;   // [144][128]

  // ---- Layer 1: [16x64] @ [64x128] ----
  half8_t a0, a1;
  {
    const float* xr = x + (size_t)(r0 + cl) * 64 + q * 8;
    floatx4 v0 = *(const floatx4*)(xr);
    floatx4 v1 = *(const floatx4*)(xr + 4);
    floatx4 v2 = *(const floatx4*)(xr + 32);
    floatx4 v3 = *(const floatx4*)(xr + 36);
#pragma unroll
    for (int i = 0; i < 4; ++i) {
      a0[i] = (f16)v0[i]; a0[i + 4] = (f16)v1[i];
      a1[i] = (f16)v2[i]; a1[i + 4] = (f16)v3[i];
    }
  }
#pragma unroll
  for (int c8 = 0; c8 < 8; ++c8) {
    int c = c8 * 16 + cl;
    half8_t w0 = *(const half8_t*)(w1t + c * 64 + q * 8);
    half8_t w1v = *(const half8_t*)(w1t + c * 64 + 32 + q * 8);
    floatx4 acc = {0.f, 0.f, 0.f, 0.f};
    acc = __builtin_amdgcn_mfma_f32_16x16x32_f16(a0, w0, acc, 0, 0, 0);
    acc = __builtin_amdgcn_mfma_f32_16x16x32_f16(a1, w1v, acc, 0, 0, 0);
    float bias = b1[c];
#pragma unroll
    for (int i = 0; i < 4; ++i) {
      float v = acc[i] + bias;
      v = v > 0.f ? v : 0.01f * v;  // LeakyReLU
      hb[q * 4 + i][c] = (f16)v;
    }
  }

  // ---- Layer 2: [16x128] @ [128x128] ----
  half8_t ha[4];
#pragma unroll
  for (int ks = 0; ks < 4; ++ks)
    ha[ks] = *(const half8_t*)(&hb[cl][ks * 32 + q * 8]);
#pragma unroll
  for (int c8 = 0; c8 < 8; ++c8) {
    int c = c8 * 16 + cl;
    floatx4 acc = {0.f, 0.f, 0.f, 0.f};
#pragma unroll
    for (int ks = 0; ks < 4; ++ks) {
      half8_t wv = *(const half8_t*)(w2t + c * 128 + ks * 32 + q * 8);
      acc = __builtin_amdgcn_mfma_f32_16x16x32_f16(ha[ks], wv, acc, 0, 0, 0);
    }
    float bias = b2v[c];
#pragma unroll
    for (int i = 0; i < 4; ++i) {
      float v = acc[i] + bias;
      v = v > 0.f ? v : 0.01f * v;
      hb[q * 4 + i][c] = (f16)v;  // overwrite after reads (in-order DS pipe)
    }
  }

  // ---- Layer 3: [16x128] @ [128x136] + tanh -> ldata tile in LDS ----
#pragma unroll
  for (int ks = 0; ks < 4; ++ks)
    ha[ks] = *(const half8_t*)(&hb[cl][ks * 32 + q * 8]);
#pragma unroll
  for (int c8 = 0; c8 < 9; ++c8) {
    int c = c8 * 16 + cl;  // 0..143
    floatx4 acc = {0.f, 0.f, 0.f, 0.f};
#pragma unroll
    for (int ks = 0; ks < 4; ++ks) {
      half8_t wv = *(const half8_t*)(w3t + c * 128 + ks * 32 + q * 8);
      acc = __builtin_amdgcn_mfma_f32_16x16x32_f16(ha[ks], wv, acc, 0, 0, 0);
    }
    if (c < 136) {
      float bias = b3[c];
#pragma unroll
      for (int i = 0; i < 4; ++i)
        hb[q * 4 + i][c] = (f16)fast_tanh(acc[i] + bias);
    }
  }

  // ---- Phase B: per-row 16x16 double-expm (tri indices hoisted) ----
  unsigned triOff[4];
  floatx4 I4, c4v;
#pragma unroll
  for (int i = 0; i < 4; ++i) {
    int k = q * 4 + i;
    int hi = cl > k ? cl : k;
    int lo = cl + k - hi;
    triOff[i] = (unsigned)(hi * (hi + 1) / 2 + lo) * 2u;
    bool d = (cl == k);
    I4[i] = d ? 1.f : 0.f;
    c4v[i] = d ? 4.f : 2.f;  // b = 2*Q: offdiag 2*l, diag 4*l
  }

  for (int mt = 0; mt < 16; ++mt) {
    const char* base = (const char*)&hb[mt][0];
    floatx4 b;
#pragma unroll
    for (int i = 0; i < 4; ++i)
      b[i] = c4v[i] * (float)*(const f16*)(base + triOff[i]);

    // expm #1: p = expm(2Q - m1 I);  Z/2 = e^{m1}/2 * p (exact algebra)
    float m1;
    floatx4 p = expm_c(b, I4, m1);
    float fac = __builtin_amdgcn_exp2f(m1 * 1.4426950408889634f - 1.0f);
    // expm #2: shift constant cancels in the final Frobenius normalization
    float m2;
    p = expm_c(p * fac, I4, m2);

    float n2 = wsum(p[0] * p[0] + p[1] * p[1] + p[2] * p[2] + p[3] * p[3]);
    float inv = __builtin_amdgcn_rsqf(n2);
    floatx4 o = p * inv;
    // value_i = M[cl][4q+i] -> out[mat*256 + cl*16 + 4q + i]
    *(floatx4*)(out + (size_t)(r0 + mt) * 256 + cl * 16 + q * 4) = o;
  }
}

// ------------------------------------------------------------------
extern "C" void kernel_launch(void* const* d_in, const int* in_sizes, int n_in,
                              void* d_out, int out_size, void* d_ws,
                              size_t ws_size, hipStream_t stream) {
  const float* x = (const float*)d_in[0];
  const float* W1 = (const float*)d_in[1];
  const float* b1 = (const float*)d_in[2];
  const float* W2 = (const float*)d_in[3];
  const float* b2 = (const float*)d_in[4];
  const float* W3 = (const float*)d_in[5];
  const float* b3 = (const float*)d_in[6];
  float* out = (float*)d_out;
  f16* wt = (f16*)d_ws;

  prep_weights<<<168, 256, 0, stream>>>(W1, W2, W3, wt);
  fused_kernel<<<4096, 64, 0, stream>>>(x, b1, b2, b3, wt, out);
}